// Round 16
// baseline (297.081 us; speedup 1.0000x reference)
//
#include <hip/hip_runtime.h>
#include <hip/hip_bf16.h>
#include <stdint.h>

#define IN_F 2048
#define OUT_F 128
#define KD 32
#define NR 256
#define OC 2176          // IN_F + OUT_F
#define OD 4096          // OUT_F * KD (T row stride)
#define THRESH 32.0f
#define GRID 512

typedef __bf16 bf16x8 __attribute__((ext_vector_type(8)));
typedef __bf16 bf16x4 __attribute__((ext_vector_type(4)));
typedef float  f32x4  __attribute__((ext_vector_type(4)));

// ---------------------------------------------------------------------------
// Grid barrier in module globals (NOT d_ws: ws is poisoned to 0xAA; module
// globals init to 0 and the barrier self-resets g_cnt, uses g_gen only via
// equality -> correct for any starting gen; deterministic every call).
// Requires all GRID blocks co-resident: 512 blocks, 256 thr,
// __launch_bounds__(256,2), LDS 13 KB -> 2 blocks/CU schedulable on 256 CUs.
// ---------------------------------------------------------------------------
__device__ uint32_t g_cnt = 0;
__device__ uint32_t g_gen = 0;

__device__ __forceinline__ void gridbar() {
    __syncthreads();
    __threadfence();                       // release prior global writes (cross-XCD)
    if (threadIdx.x == 0) {
        uint32_t g = __hip_atomic_load(&g_gen, __ATOMIC_ACQUIRE, __HIP_MEMORY_SCOPE_AGENT);
        uint32_t a = __hip_atomic_fetch_add(&g_cnt, 1u, __ATOMIC_ACQ_REL, __HIP_MEMORY_SCOPE_AGENT);
        if (a == GRID - 1u) {
            __hip_atomic_store(&g_cnt, 0u, __ATOMIC_RELAXED, __HIP_MEMORY_SCOPE_AGENT);
            __hip_atomic_fetch_add(&g_gen, 1u, __ATOMIC_RELEASE, __HIP_MEMORY_SCOPE_AGENT);
        } else {
            while (__hip_atomic_load(&g_gen, __ATOMIC_ACQUIRE, __HIP_MEMORY_SCOPE_AGENT) == g)
                __builtin_amdgcn_s_sleep(2);
        }
    }
    __syncthreads();
    __threadfence();                       // acquire side
}

// ---------------------------------------------------------------------------
// Mega kernel: P1 (tproj x2 + prep) -> bar -> P2 (sgemm x2) -> bar -> P3 screen.
// Phase bodies verbatim R15 modulo work-index sourcing.
// ---------------------------------------------------------------------------
__global__ __launch_bounds__(256, 2) void mega_kernel(const float* __restrict__ x,
                                                      const float* __restrict__ Tm,
                                                      float* __restrict__ out,
                                                      __bf16* __restrict__ xb2,
                                                      __bf16* __restrict__ Tb,
                                                      float* __restrict__ Pp) {
    __shared__ __bf16 o4[4][64][8];        // 4 KB (P1 transpose tile)
    __shared__ float P8s[256][8];          // 8 KB (P3)
    __shared__ float part[4][64];          // 1 KB (P3)

    const int bid  = blockIdx.x;
    const int tid  = threadIdx.x;
    const int lane = tid & 63;
    const int wid  = tid >> 6;
    const int fr   = lane & 15, fg = lane >> 4;

    // ======== Phase 1a: tproj (2 work-units per block) ========
    #pragma unroll 1
    for (int r = 0; r < 2; ++r) {
        if (r) __syncthreads();            // o4 reuse across iterations
        const int wb = bid * 2 + r;        // 0..1023
        const int kt = wb >> 4;            // 0..63 : 32-k tile
        const int fo = wb & 15;            // 0..15 : 8-f group
        const int kl = tid >> 3;           // 0..31
        const int fl = tid & 7;            // 0..7
        const int f  = fo * 8 + fl;
        const int k  = kt * 32 + kl;

        float v[32];
        const float* src = Tm + (size_t)k * OD + f * KD;
        #pragma unroll
        for (int q = 0; q < 8; ++q) {
            f32x4 w = *reinterpret_cast<const f32x4*>(src + q * 4);
            v[q * 4]     = w[0];
            v[q * 4 + 1] = w[1];
            v[q * 4 + 2] = w[2];
            v[q * 4 + 3] = w[3];
        }

        float s1[16], d1[16];
        #pragma unroll
        for (int e = 0; e < 16; ++e) { s1[e] = v[2*e] + v[2*e+1]; d1[e] = v[2*e] - v[2*e+1]; }
        float s2[8], d2[8];
        #pragma unroll
        for (int e = 0; e < 8; ++e)  { s2[e] = s1[2*e] + s1[2*e+1]; d2[e] = s1[2*e] - s1[2*e+1]; }
        float s3[4], d3[4];
        #pragma unroll
        for (int e = 0; e < 4; ++e)  { s3[e] = s2[2*e] + s2[2*e+1]; d3[e] = s2[2*e] - s2[2*e+1]; }
        float s4[2], d4[2];
        #pragma unroll
        for (int e = 0; e < 2; ++e)  { s4[e] = s3[2*e] + s3[2*e+1]; d4[e] = s3[2*e] - s3[2*e+1]; }
        const float s5 = s4[0] + s4[1];
        const float d5 = s4[0] - s4[1];

        float pr[8];
        pr[0] = s5;
        { float s = 0.f;
          #pragma unroll
          for (int e = 0; e < 16; ++e) s += d1[e];
          pr[1] = s; }
        { float s = 0.f;
          #pragma unroll
          for (int e = 0; e < 8; ++e) s += d2[e];
          pr[2] = s; }
        pr[3] = (d3[0] + d3[1]) + (d3[2] + d3[3]);
        pr[4] = d4[0] + d4[1];
        pr[5] = d5;
        { float s = 0.f;
          #pragma unroll
          for (int g = 0; g < 8; ++g) s += d1[2*g] - d1[2*g+1];
          pr[6] = s; }
        pr[7] = s3[0] - s3[1] - s3[2] + s3[3];

        const int li0 = ((kl >> 3) & 3) * 16 + (fl & 1) * 8;
        #pragma unroll
        for (int p = 0; p < 8; ++p)
            o4[fl >> 1][li0 + p][kl & 7] = (__bf16)pr[p];
        __syncthreads();

        const int cl = tid >> 6, l = tid & 63;
        const size_t c0 = (size_t)kt * 64 + fo * 4;
        *reinterpret_cast<bf16x8*>(Tb + (c0 + cl) * 512 + l * 8) =
            *reinterpret_cast<const bf16x8*>(&o4[cl][l][0]);
    }

    // ======== Phase 1b: prep (float4 granularity, all 512 blocks) ========
    {
        const int u   = bid * 256 + tid;   // 0..131071
        const int row = u & 255;
        const int c8  = u >> 8;            // 0..511 (4-float chunks)
        const int k0  = c8 * 4;
        float4 v = *reinterpret_cast<const float4*>(&x[row * IN_F + k0]);
        *reinterpret_cast<float4*>(&out[row * OC + k0]) = v;
        bf16x4 p = { (__bf16)v.x, (__bf16)v.y, (__bf16)v.z, (__bf16)v.w };
        *reinterpret_cast<bf16x4*>(&xb2[((size_t)(c8 >> 1) * 256 + row) * 8 + (c8 & 1) * 4]) = p;
    }

    gridbar();

    // ======== Phase 2: sgemm (2 work-units per block) ========
    #pragma unroll 1
    for (int r = 0; r < 2; ++r) {
        const int w  = bid * 2 + r;        // 0..1023
        const int co = w & 31;
        const int bn = (w >> 5) & 3;
        const int ks = w >> 7;
        const int ot0 = co * 2;
        const int n0  = bn * 64 + wid * 16;
        const int h0  = ks * 8;
        const int n0fr = n0 + fr;
        const int l = lane;

        f32x4 acc0 = {}, acc1 = {};

#define SLOAD(sv, h) do {                                                      \
        (sv).a = *reinterpret_cast<const bf16x8*>(                             \
            xb2 + ((size_t)((h) * 4 + fg) * 256 + n0fr) * 8);                  \
        const __bf16* bb_ = Tb + (((size_t)(h) * 64 + ot0) * 64 + l) * 8;      \
        (sv).b0 = *reinterpret_cast<const bf16x8*>(bb_);                       \
        (sv).b1 = *reinterpret_cast<const bf16x8*>(bb_ + 512);                 \
    } while (0)
#define CMP(s) do { \
        acc0 = __builtin_amdgcn_mfma_f32_16x16x32_bf16((s).a, (s).b0, acc0, 0, 0, 0); \
        acc1 = __builtin_amdgcn_mfma_f32_16x16x32_bf16((s).a, (s).b1, acc1, 0, 0, 0); \
    } while (0)

        struct { bf16x8 a, b0, b1; } s0, s1, s2;
        SLOAD(s0, h0 + 0);
        SLOAD(s1, h0 + 1);
        SLOAD(s2, h0 + 2);

        CMP(s0); SLOAD(s0, h0 + 3);
        CMP(s1); SLOAD(s1, h0 + 4);
        CMP(s2); SLOAD(s2, h0 + 5);
        CMP(s0); SLOAD(s0, h0 + 6);
        CMP(s1); SLOAD(s1, h0 + 7);
        CMP(s2);
        CMP(s0);
        CMP(s1);
#undef SLOAD
#undef CMP

        float* dst = Pp + ((size_t)ks << 18);          // ks * 1024 * 256
        const int o0 = co * 32;
        const int nb = n0 + fg * 4;
        *reinterpret_cast<f32x4*>(&dst[(size_t)(o0 + fr)      * NR + nb]) = acc0;
        *reinterpret_cast<f32x4*>(&dst[(size_t)(o0 + 16 + fr) * NR + nb]) = acc1;
    }

    gridbar();

    // ======== Phase 3: screen ========
    {
        const int f  = bid >> 2;           // 0..127
        const int jq = bid & 3;            // 0..3
        const int j  = jq * 64 + lane;

        #pragma unroll
        for (int p = 0; p < 8; ++p) {
            float s = 0.f;
            #pragma unroll
            for (int ks = 0; ks < 8; ++ks)
                s += Pp[((size_t)ks << 18) + (size_t)(f * 8 + p) * NR + tid];
            P8s[tid][p] = s;
        }
        __syncthreads();

        const f32x4 qj0 = *reinterpret_cast<const f32x4*>(&P8s[j][0]);
        const f32x4 qj1 = *reinterpret_cast<const f32x4*>(&P8s[j][4]);

        float acc = 0.f;
        const int i0 = wid * 64;
        #pragma unroll 2
        for (int ii = 0; ii < 64; ++ii) {
            const int i = i0 + ii;
            f32x4 r0 = *reinterpret_cast<const f32x4*>(&P8s[i][0]);
            f32x4 r1 = *reinterpret_cast<const f32x4*>(&P8s[i][4]);
            f32x4 d0 = r0 - qj0;
            f32x4 d1 = r1 - qj1;
            float m0 = fmaxf(fmaxf(fabsf(d0[0]), fabsf(d0[1])), fabsf(d0[2]));
            float m1 = fmaxf(fmaxf(fabsf(d0[3]), fabsf(d1[0])), fabsf(d1[1]));
            float m2 = fmaxf(fabsf(d1[2]), fabsf(d1[3]));
            const float mx = fmaxf(fmaxf(m0, m1), m2);

            const bool ok = (mx < THRESH) && (i != j);
            if (__builtin_expect(__any(ok), 0)) {
                if (ok) {
                    f32x4 ad[8] = {};
                    const float* xi = x + (size_t)i * IN_F;
                    const float* xj = x + (size_t)j * IN_F;
                    for (int k = 0; k < IN_F; ++k) {
                        const float dk = xi[k] - xj[k];
                        const float* tr = Tm + (size_t)k * OD + f * KD;
                        #pragma unroll
                        for (int q = 0; q < 8; ++q) {
                            f32x4 tv = *reinterpret_cast<const f32x4*>(tr + q * 4);
                            ad[q] += dk * tv;
                        }
                    }
                    float norm = 0.f;
                    #pragma unroll
                    for (int q = 0; q < 8; ++q)
                        norm += fabsf(ad[q][0]) + fabsf(ad[q][1])
                              + fabsf(ad[q][2]) + fabsf(ad[q][3]);
                    acc += __expf(-norm);
                }
            }
        }

        if (wid == jq) acc += 1.0f;        // diagonal exp(0)=1, exact

        part[wid][lane] = acc;
        __syncthreads();
        if (tid < 64) {
            float s = part[0][tid] + part[1][tid] + part[2][tid] + part[3][tid];
            out[(jq * 64 + tid) * OC + IN_F + f] = s;
        }
    }
}

extern "C" void kernel_launch(void* const* d_in, const int* in_sizes, int n_in,
                              void* d_out, int out_size, void* d_ws, size_t ws_size,
                              hipStream_t stream) {
    const float* x  = (const float*)d_in[0];   // [256, 2048] f32
    const float* Tm = (const float*)d_in[1];   // [2048, 4096] f32
    float* out = (float*)d_out;                // [256, 2176] f32
    char*  ws  = (char*)d_ws;

    __bf16* Tb  = (__bf16*)ws;                      // 4 MB  Tproj B-frag image
    __bf16* xb2 = (__bf16*)(ws + (4u << 20));       // 1 MB  x A-frag image
    float*  Pp  = (float*)(ws + (5u << 20));        // 8 MB  8 f32 o'-major partials

    mega_kernel<<<dim3(GRID), 256, 0, stream>>>(x, Tm, out, xb2, Tb, Pp);
}

// Round 17
// 28.479 us; speedup vs baseline: 10.4316x; 10.4316x over previous
//
#include <hip/hip_runtime.h>
#include <hip/hip_bf16.h>
#include <stdint.h>

#define IN_F 2048
#define OUT_F 128
#define KD 32
#define NR 256
#define OC 2176          // IN_F + OUT_F
#define OD 4096          // OUT_F * KD (T row stride)
#define THRESH 32.0f
#define KSN 16           // k-slices of 128
#define OPN (1024 * 256) // elems per Pp partial

typedef __bf16 bf16x8 __attribute__((ext_vector_type(8)));
typedef __bf16 bf16x4 __attribute__((ext_vector_type(4)));
typedef float  f32x4  __attribute__((ext_vector_type(4)));
typedef uint16_t u16x8 __attribute__((ext_vector_type(8)));

// ---------------------------------------------------------------------------
// K1: fused tproj + sgemm + x-copy. Block = (ks in [0,16), fo in [0,32)).
// Per block: T slab (128k x 4f x 32d, read ONCE) -> butterfly-FWHT (R15
// verbatim) -> Tproj LDS Bs[32 o'][136]; x staged inline per 32k chunk as
// MFMA A-frags (dbuf); 8 MFMA/wave/chunk; epilogue bf16 Pp[ks][o'][n].
// 512 blocks x 256 thr (2 blocks/CU). No cross-block dependencies.
// ---------------------------------------------------------------------------
__global__ __launch_bounds__(256, 2) void fused_kernel(const float* __restrict__ x,
                                                       const float* __restrict__ Tm,
                                                       float* __restrict__ out,
                                                       __bf16* __restrict__ Pp) {
    __shared__ __bf16 Bs[32][136];       // Tproj slab [o'_local][k_local], pad 8
    __shared__ __bf16 As[2][4][256][8];  // x A-frag dbuf (32 KB)

    const int tid  = threadIdx.x;
    const int lane = tid & 63;
    const int wid  = tid >> 6;
    const int fr   = lane & 15, fg = lane >> 4;
    const int bid  = blockIdx.x;
    const int ks   = bid & 15;
    const int fo   = bid >> 4;           // f-group of 4
    const int k0   = ks * 128;

    // ---- x -> out copy (block covers 4 KB: row bid>>1, half bid&1)
    {
        const int row = bid >> 1;
        const int off = (bid & 1) * 1024 + tid * 4;
        float4 v = *reinterpret_cast<const float4*>(&x[row * IN_F + off]);
        *reinterpret_cast<float4*>(&out[row * OC + off]) = v;
    }

    // ---- issue x chunk-0 loads early (latency hides under butterflies)
    float4 xs[8];
    const int kslot = tid & 7;
    const int nrow8 = tid >> 3;          // n = p*32 + nrow8
    #pragma unroll
    for (int p = 0; p < 8; ++p)
        xs[p] = *reinterpret_cast<const float4*>(&x[(p * 32 + nrow8) * IN_F + k0 + kslot * 4]);

    // ---- tproj: 2 (k,f) pairs per thread (sequential; keeps VGPR < 128)
    #pragma unroll 1
    for (int r = 0; r < 2; ++r) {
        const int idx = r * 256 + tid;
        const int fl  = idx & 3;
        const int kl  = idx >> 2;        // 0..127
        const float* src = Tm + (size_t)(k0 + kl) * OD + (fo * 4 + fl) * KD;

        float v[32];
        #pragma unroll
        for (int q = 0; q < 8; ++q) {
            f32x4 w = *reinterpret_cast<const f32x4*>(src + q * 4);
            v[q * 4]     = w[0];
            v[q * 4 + 1] = w[1];
            v[q * 4 + 2] = w[2];
            v[q * 4 + 3] = w[3];
        }

        float s1[16], d1[16];
        #pragma unroll
        for (int e = 0; e < 16; ++e) { s1[e] = v[2*e] + v[2*e+1]; d1[e] = v[2*e] - v[2*e+1]; }
        float s2[8], d2[8];
        #pragma unroll
        for (int e = 0; e < 8; ++e)  { s2[e] = s1[2*e] + s1[2*e+1]; d2[e] = s1[2*e] - s1[2*e+1]; }
        float s3[4], d3[4];
        #pragma unroll
        for (int e = 0; e < 4; ++e)  { s3[e] = s2[2*e] + s2[2*e+1]; d3[e] = s2[2*e] - s2[2*e+1]; }
        float s4[2], d4[2];
        #pragma unroll
        for (int e = 0; e < 2; ++e)  { s4[e] = s3[2*e] + s3[2*e+1]; d4[e] = s3[2*e] - s3[2*e+1]; }
        const float s5 = s4[0] + s4[1];
        const float d5 = s4[0] - s4[1];

        float pr[8];
        pr[0] = s5;
        { float s = 0.f;
          #pragma unroll
          for (int e = 0; e < 16; ++e) s += d1[e];
          pr[1] = s; }
        { float s = 0.f;
          #pragma unroll
          for (int e = 0; e < 8; ++e) s += d2[e];
          pr[2] = s; }
        pr[3] = (d3[0] + d3[1]) + (d3[2] + d3[3]);
        pr[4] = d4[0] + d4[1];
        pr[5] = d5;
        { float s = 0.f;
          #pragma unroll
          for (int g = 0; g < 8; ++g) s += d1[2*g] - d1[2*g+1];
          pr[6] = s; }
        pr[7] = s3[0] - s3[1] - s3[2] + s3[3];

        #pragma unroll
        for (int p = 0; p < 8; ++p)
            Bs[fl * 8 + p][kl] = (__bf16)pr[p];
    }

    // ---- write x chunk 0 into As[0]
    #pragma unroll
    for (int p = 0; p < 8; ++p) {
        bf16x4 b = { (__bf16)xs[p].x, (__bf16)xs[p].y, (__bf16)xs[p].z, (__bf16)xs[p].w };
        *reinterpret_cast<bf16x4*>(&As[0][kslot >> 1][p * 32 + nrow8][(kslot & 1) * 4]) = b;
    }
    __syncthreads();

    // ---- MFMA loop: 4 chunks of 32 k; acc[mi][oi], wave owns 64 n x 32 o'
    f32x4 acc[4][2] = {};

    #pragma unroll 1
    for (int c = 0; c < 4; ++c) {
        const int buf = c & 1;
        if (c < 3) {
            #pragma unroll
            for (int p = 0; p < 8; ++p)
                xs[p] = *reinterpret_cast<const float4*>(
                    &x[(p * 32 + nrow8) * IN_F + k0 + (c + 1) * 32 + kslot * 4]);
        }

        bf16x8 bfrag[2];
        #pragma unroll
        for (int oi = 0; oi < 2; ++oi)
            bfrag[oi] = *reinterpret_cast<const bf16x8*>(&Bs[oi * 16 + fr][c * 32 + fg * 8]);
        #pragma unroll
        for (int mi = 0; mi < 4; ++mi) {
            bf16x8 af = *reinterpret_cast<const bf16x8*>(&As[buf][fg][wid * 64 + mi * 16 + fr][0]);
            acc[mi][0] = __builtin_amdgcn_mfma_f32_16x16x32_bf16(af, bfrag[0], acc[mi][0], 0, 0, 0);
            acc[mi][1] = __builtin_amdgcn_mfma_f32_16x16x32_bf16(af, bfrag[1], acc[mi][1], 0, 0, 0);
        }

        if (c < 3) {
            __syncthreads();             // all waves done with As[buf^1] readers
            #pragma unroll
            for (int p = 0; p < 8; ++p) {
                bf16x4 b = { (__bf16)xs[p].x, (__bf16)xs[p].y, (__bf16)xs[p].z, (__bf16)xs[p].w };
                *reinterpret_cast<bf16x4*>(&As[buf ^ 1][kslot >> 1][p * 32 + nrow8][(kslot & 1) * 4]) = b;
            }
            __syncthreads();
        }
    }

    // ---- epilogue: Pp[ks][o' = fo*32 + oi*16 + fr][n = wid*64+mi*16+fg*4+r] bf16
    __bf16* dst = Pp + (size_t)ks * OPN;
    #pragma unroll
    for (int mi = 0; mi < 4; ++mi) {
        #pragma unroll
        for (int oi = 0; oi < 2; ++oi) {
            const int op = fo * 32 + oi * 16 + fr;
            const int nb = wid * 64 + mi * 16 + fg * 4;
            bf16x4 v = { (__bf16)acc[mi][oi][0], (__bf16)acc[mi][oi][1],
                         (__bf16)acc[mi][oi][2], (__bf16)acc[mi][oi][3] };
            *reinterpret_cast<bf16x4*>(&dst[(size_t)op * NR + nb]) = v;
        }
    }
}

// ---------------------------------------------------------------------------
// K2: screen (R15-proven hot loop). Staging: vectorized u16x8 reads of the
// 16 bf16 partials (contiguous 4 KB slab per (f, ks)); P8s[n][p] in LDS.
// Drop pair when max_p |dproj| > 32 (sound: L1 >= |dproj|; margins leave
// dropped terms <= 256*e^-17 ~ 1e-5 << 0.099). Survivor -> exact from x,T.
// ---------------------------------------------------------------------------
__global__ __launch_bounds__(256, 2) void screen_kernel(const __bf16* __restrict__ Pp,
                                                        const float* __restrict__ x,
                                                        const float* __restrict__ Tm,
                                                        float* __restrict__ out) {
    __shared__ float P8s[256][8];
    __shared__ float part[4][64];

    const int f    = blockIdx.x;
    const int jq   = blockIdx.y;
    const int tid  = threadIdx.x;
    const int lane = tid & 63;
    const int wid  = tid >> 6;
    const int j    = jq * 64 + lane;

    // stage: thread t sums (p = t>>5, n = (t&31)*8 .. +8) over 16 partials
    {
        const int p  = tid >> 5;
        const int n0 = (tid & 31) * 8;
        const uint16_t* base = reinterpret_cast<const uint16_t*>(Pp)
                             + (size_t)(f * 8 + p) * NR + n0;
        float a[8] = {};
        #pragma unroll
        for (int ks = 0; ks < KSN; ++ks) {
            u16x8 v = *reinterpret_cast<const u16x8*>(base + (size_t)ks * OPN);
            #pragma unroll
            for (int e = 0; e < 8; ++e)
                a[e] += __builtin_bit_cast(float, (uint32_t)v[e] << 16);
        }
        #pragma unroll
        for (int e = 0; e < 8; ++e)
            P8s[n0 + e][p] = a[e];
    }
    __syncthreads();

    const f32x4 qj0 = *reinterpret_cast<const f32x4*>(&P8s[j][0]);
    const f32x4 qj1 = *reinterpret_cast<const f32x4*>(&P8s[j][4]);

    float acc = 0.f;
    const int i0 = wid * 64;
    #pragma unroll 2
    for (int ii = 0; ii < 64; ++ii) {
        const int i = i0 + ii;
        f32x4 r0 = *reinterpret_cast<const f32x4*>(&P8s[i][0]);
        f32x4 r1 = *reinterpret_cast<const f32x4*>(&P8s[i][4]);
        f32x4 d0 = r0 - qj0;
        f32x4 d1 = r1 - qj1;
        float m0 = fmaxf(fmaxf(fabsf(d0[0]), fabsf(d0[1])), fabsf(d0[2]));
        float m1 = fmaxf(fmaxf(fabsf(d0[3]), fabsf(d1[0])), fabsf(d1[1]));
        float m2 = fmaxf(fabsf(d1[2]), fabsf(d1[3]));
        const float mx = fmaxf(fmaxf(m0, m1), m2);

        const bool ok = (mx < THRESH) && (i != j);
        if (__builtin_expect(__any(ok), 0)) {
            if (ok) {
                f32x4 ad[8] = {};
                const float* xi = x + (size_t)i * IN_F;
                const float* xj = x + (size_t)j * IN_F;
                for (int k = 0; k < IN_F; ++k) {
                    const float dk = xi[k] - xj[k];
                    const float* tr = Tm + (size_t)k * OD + f * KD;
                    #pragma unroll
                    for (int q = 0; q < 8; ++q) {
                        f32x4 tv = *reinterpret_cast<const f32x4*>(tr + q * 4);
                        ad[q] += dk * tv;
                    }
                }
                float norm = 0.f;
                #pragma unroll
                for (int q = 0; q < 8; ++q)
                    norm += fabsf(ad[q][0]) + fabsf(ad[q][1])
                          + fabsf(ad[q][2]) + fabsf(ad[q][3]);
                acc += __expf(-norm);
            }
        }
    }

    if (wid == jq) acc += 1.0f;          // diagonal exp(0)=1, exact

    part[wid][lane] = acc;
    __syncthreads();
    if (tid < 64) {
        float s = part[0][tid] + part[1][tid] + part[2][tid] + part[3][tid];
        out[(jq * 64 + tid) * OC + IN_F + f] = s;
    }
}

extern "C" void kernel_launch(void* const* d_in, const int* in_sizes, int n_in,
                              void* d_out, int out_size, void* d_ws, size_t ws_size,
                              hipStream_t stream) {
    const float* x  = (const float*)d_in[0];   // [256, 2048] f32
    const float* Tm = (const float*)d_in[1];   // [2048, 4096] f32
    float* out = (float*)d_out;                // [256, 2176] f32

    __bf16* Pp = (__bf16*)d_ws;                // 8 MB: 16 bf16 o'-major partials

    fused_kernel<<<dim3(512), 256, 0, stream>>>(x, Tm, out, Pp);
    screen_kernel<<<dim3(128, 4), 256, 0, stream>>>(Pp, x, Tm, out);
}